// Round 15
// baseline (214.889 us; speedup 1.0000x reference)
//
#include <hip/hip_runtime.h>
#include <stdint.h>

typedef int i32x4 __attribute__((ext_vector_type(4)));

#define K_DIM 1024
#define BM 256
#define BN 128
#define NKT 16   // K-tiles of 64

// Fragment-ordered int8 operand layout (producers aquant/wquant <-> consumer GEMM):
// fragment (F = row/16, T = k/64) is 1KB at offset ((F*16)+T)*1024; byte b
// (l=b>>4, j=b&15) holds value[row=F*16+(l&15)][k=T*64+(l>>4)*16+j].
// -> A gld_lds reads are 1KB contiguous; B fragments load straight to registers.

// ---------------- helpers ----------------
__device__ __forceinline__ int quant1(float v, float inv) {
  float t = rintf(v * inv);                 // round half-to-even, matches jnp.round
  t = fminf(fmaxf(t, -128.0f), 127.0f);     // clip(-n-1, n)
  return (int)t;
}

__device__ __forceinline__ void gld_lds16(const signed char* g, signed char* l) {
  typedef const __attribute__((address_space(1))) unsigned int* gp_t;
  typedef __attribute__((address_space(3))) unsigned int* lp_t;
  __builtin_amdgcn_global_load_lds((gp_t)(const void*)g, (lp_t)(void*)l, 16, 0, 0);
}

#define SB __builtin_amdgcn_sched_barrier(0)
#define BAR __builtin_amdgcn_s_barrier()
#define WAIT_LGKM0 asm volatile("s_waitcnt lgkmcnt(0)" ::: "memory")

// ---------------- 1a) absmax partials ----------------
__global__ void absmax_part(const float* __restrict__ x, float* __restrict__ parts,
                            long long n4) {
  long long i = (long long)blockIdx.x * blockDim.x + threadIdx.x;
  const long long stride = (long long)gridDim.x * blockDim.x;
  const float4* x4 = (const float4*)x;
  float m = 0.0f;
  for (; i < n4; i += stride) {
    float4 v = x4[i];
    m = fmaxf(m, fmaxf(fmaxf(fabsf(v.x), fabsf(v.y)), fmaxf(fabsf(v.z), fabsf(v.w))));
  }
#pragma unroll
  for (int off = 32; off > 0; off >>= 1) m = fmaxf(m, __shfl_down(m, off, 64));
  __shared__ float sm[4];
  const int lane = threadIdx.x & 63, wid = threadIdx.x >> 6;
  if (lane == 0) sm[wid] = m;
  __syncthreads();
  if (threadIdx.x == 0)
    parts[blockIdx.x] = fmaxf(fmaxf(sm[0], sm[1]), fmaxf(sm[2], sm[3]));
}

// ---------------- 1b) absmax final reduce ----------------
__global__ void absmax_fin(const float* __restrict__ parts, unsigned int* __restrict__ amax_u,
                           int nparts) {
  const int t = threadIdx.x;
  float m = 0.0f;
  for (int i = t; i < nparts; i += 256) m = fmaxf(m, parts[i]);
#pragma unroll
  for (int off = 32; off > 0; off >>= 1) m = fmaxf(m, __shfl_down(m, off, 64));
  __shared__ float sm[4];
  const int lane = t & 63, wid = t >> 6;
  if (lane == 0) sm[wid] = m;
  __syncthreads();
  if (t == 0)
    amax_u[0] = __float_as_uint(fmaxf(fmaxf(sm[0], sm[1]), fmaxf(sm[2], sm[3])));
}

// ---------------- 2) per-channel weight quant + bias (frag-ordered wq) ----------------
__global__ void wquant_kernel(const float* __restrict__ w, const float* __restrict__ bias,
                              const unsigned int* __restrict__ amax_u,
                              signed char* __restrict__ wq,
                              float* __restrict__ bscale, float* __restrict__ bint) {
  const int o = blockIdx.x;
  const int t = threadIdx.x;          // handles k = 4t .. 4t+3
  float4 v = ((const float4*)(w + (size_t)o * K_DIM))[t];
  float m = fmaxf(fmaxf(fabsf(v.x), fabsf(v.y)), fmaxf(fabsf(v.z), fabsf(v.w)));
#pragma unroll
  for (int off = 32; off > 0; off >>= 1) m = fmaxf(m, __shfl_down(m, off, 64));
  __shared__ float sm[4];
  __shared__ float s_scale;
  const int lane = t & 63, wid = t >> 6;
  if (lane == 0) sm[wid] = m;
  __syncthreads();
  if (t == 0) {
    float wm = fmaxf(fmaxf(sm[0], sm[1]), fmaxf(sm[2], sm[3]));
    float wsc = fmaxf(wm, 1e-8f) / 127.0f;
    float asc = fmaxf(__uint_as_float(*amax_u), 1e-8f) / 127.0f;
    float bsc = wsc * asc;
    bscale[o] = bsc;
    bint[o] = rintf(bias[o] / bsc);
    s_scale = wsc;
  }
  __syncthreads();
  const float inv = 1.0f / s_scale;
  int q0 = quant1(v.x, inv), q1 = quant1(v.y, inv), q2 = quant1(v.z, inv), q3 = quant1(v.w, inv);
  unsigned int p = (unsigned)(q0 & 255) | ((unsigned)(q1 & 255) << 8) |
                   ((unsigned)(q2 & 255) << 16) | ((unsigned)(q3 & 255) << 24);
  const int F = o >> 4, T = t >> 4;
  const int l = (((t >> 2) & 3) << 4) | (o & 15);
  const int j = (t << 2) & 15;
  *(unsigned int*)(wq + (((size_t)F << 14) + (T << 10) + (l << 4) + j)) = p;
}

// ---------------- 3) activation quant (frag-ordered xq; 256B-granule reads) ----------------
__global__ void aquant_kernel(const float* __restrict__ x, const unsigned int* __restrict__ amax_u,
                              uint4* __restrict__ q16, int nchunk) {
  const float asc = fmaxf(__uint_as_float(*amax_u), 1e-8f) / 127.0f;
  const float inv = 1.0f / asc;
  int c = blockIdx.x * blockDim.x + threadIdx.x;
  const int stride = gridDim.x * blockDim.x;
  for (; c < nchunk; c += stride) {
    const int l = c & 63, T = (c >> 6) & 15, F = c >> 10;
    const size_t src = (((size_t)(F << 4) + (l & 15)) << 10) + (T << 6) + ((l >> 4) << 4);
    const float4* s4 = (const float4*)(x + src);
    unsigned int r[4];
#pragma unroll
    for (int q = 0; q < 4; q++) {
      float4 v = s4[q];
      int q0 = quant1(v.x, inv), q1 = quant1(v.y, inv), q2 = quant1(v.z, inv), q3 = quant1(v.w, inv);
      r[q] = (unsigned)(q0 & 255) | ((unsigned)(q1 & 255) << 8) |
             ((unsigned)(q2 & 255) << 16) | ((unsigned)(q3 & 255) << 24);
    }
    q16[c] = make_uint4(r[0], r[1], r[2], r[3]);
  }
}

// ---------------- 4) int8 GEMM: R9 pipeline resized for 2 blocks/CU ----------------
// 256x128 tile, 512 thr = 8 waves (4M x 2N), wave tile 64x64, acc[4][4] (64 VGPR).
// A via LDS (4-buf, depth-3 gld_lds, 16 frags/tile staged by 8 waves x 2),
// B direct-to-regs dbuf (4 b128/wave/tile), 16 MFMA + ONE barrier per K-tile,
// counted vmcnt(8) (identical invariant to R9: 6 loads/tile).
// __launch_bounds__(512,4) -> <=128 VGPR -> 2 blocks/CU: co-resident block
// fills barrier/vmcnt stalls and hides the epilogue (the overlap all
// 1-block/CU variants lacked).
__global__ __launch_bounds__(512, 4) void gemm_kernel(
    const signed char* __restrict__ A, const signed char* __restrict__ W,
    const float* __restrict__ bscale, const float* __restrict__ bint,
    float* __restrict__ out, int M, int N, int K) {
  extern __shared__ __align__(16) signed char smem[];   // 65536 B: 4 x [16][1024] A bufs
  signed char* Abase = smem;

  // bijective XCD swizzle (gridDim.x % 8 == 0); consecutive wgid share bm (A panel)
  const int nwg = gridDim.x;
  const int orig = blockIdx.x;
  const int wgid = (orig & 7) * (nwg >> 3) + (orig >> 3);
  const int nbn = N / BN;                 // 8
  const int bm = wgid / nbn;
  const int bn = wgid % nbn;
  const int m0 = bm * BM, n0 = bn * BN;

  const int tid = threadIdx.x;
  const int lane = tid & 63;
  const int wid = tid >> 6;          // 8 waves
  const int wr = wid >> 1;           // 4 wave-rows (64 rows each)
  const int wc = wid & 1;            // 2 wave-cols (64 cols each)

  // A: wave stages frags {wid, wid+8} of each K-tile (16 frags = 256 rows)
  const signed char* gaf = A + (((size_t)(m0 >> 4) + wid) << 14) + (lane << 4);
  const size_t fs8 = (size_t)8 << 14;
  // B: wave reads its 4 n-frags (wc*4+j) straight to regs
  const signed char* gbf = W + (((size_t)(n0 >> 4) + wc * 4) << 14) + (lane << 4);

  i32x4 acc[4][4];
#pragma unroll
  for (int i = 0; i < 4; i++)
#pragma unroll
    for (int j = 0; j < 4; j++) acc[i][j] = (i32x4){0, 0, 0, 0};

  i32x4 af[4];
  i32x4 bfA[4], bfB[4];

#define LOADB(L, tt)                                                           \
  do {                                                                         \
    L[0] = *(const i32x4*)(gbf + ((size_t)0 << 14) + ((tt) << 10));            \
    L[1] = *(const i32x4*)(gbf + ((size_t)1 << 14) + ((tt) << 10));            \
    L[2] = *(const i32x4*)(gbf + ((size_t)2 << 14) + ((tt) << 10));            \
    L[3] = *(const i32x4*)(gbf + ((size_t)3 << 14) + ((tt) << 10));            \
  } while (0)

#define ISSUEA(tt)                                                             \
  do {                                                                         \
    gld_lds16(gaf + ((size_t)(tt) << 10),                                      \
              Abase + ((((tt) & 3) * 16 + wid) << 10));                        \
    gld_lds16(gaf + fs8 + ((size_t)(tt) << 10),                                \
              Abase + ((((tt) & 3) * 16 + wid + 8) << 10));                    \
  } while (0)

#define RD_A(t, i_)                                                            \
  af[i_] = *(const i32x4*)(Abase + ((((t) & 3) * 16 + wr * 4 + (i_)) << 10) + (lane << 4))

#define MFMA16U(U)                                                             \
  do {                                                                         \
    __builtin_amdgcn_s_setprio(1);                                             \
    _Pragma("unroll") for (int i_ = 0; i_ < 4; i_++)                           \
      _Pragma("unroll") for (int j_ = 0; j_ < 4; j_++)                         \
        acc[i_][j_] = __builtin_amdgcn_mfma_i32_16x16x64_i8(                   \
            af[i_], U[j_], acc[i_][j_], 0, 0, 0);                              \
    __builtin_amdgcn_s_setprio(0);                                             \
  } while (0)

#define TILE(t, U, L, DOB, DOA, VMW, DOVM)                                     \
  do {                                                                         \
    if (DOB) LOADB(L, (t) + 1);                                                \
    if (DOA) ISSUEA((t) + 3);                                                  \
    SB;                                                                        \
    RD_A(t, 0); RD_A(t, 1); RD_A(t, 2); RD_A(t, 3);                            \
    MFMA16U(U);                                                                \
    if (DOVM) { asm volatile("s_waitcnt " VMW ::: "memory"); }                 \
    SB; BAR; SB;                                                               \
  } while (0)

  // prologue: A(0..2) staged (6 loads), B(0) (4 loads); drain once, barrier.
  ISSUEA(0); ISSUEA(1); ISSUEA(2);
  LOADB(bfA, 0);
  asm volatile("s_waitcnt vmcnt(0)" ::: "memory");
  SB; BAR; SB;

  TILE(0,  bfA, bfB, 1, 1, "vmcnt(8)", 1);
  TILE(1,  bfB, bfA, 1, 1, "vmcnt(8)", 1);
  TILE(2,  bfA, bfB, 1, 1, "vmcnt(8)", 1);
  TILE(3,  bfB, bfA, 1, 1, "vmcnt(8)", 1);
  TILE(4,  bfA, bfB, 1, 1, "vmcnt(8)", 1);
  TILE(5,  bfB, bfA, 1, 1, "vmcnt(8)", 1);
  TILE(6,  bfA, bfB, 1, 1, "vmcnt(8)", 1);
  TILE(7,  bfB, bfA, 1, 1, "vmcnt(8)", 1);
  TILE(8,  bfA, bfB, 1, 1, "vmcnt(8)", 1);
  TILE(9,  bfB, bfA, 1, 1, "vmcnt(8)", 1);
  TILE(10, bfA, bfB, 1, 1, "vmcnt(8)", 1);
  TILE(11, bfB, bfA, 1, 1, "vmcnt(8)", 1);
  TILE(12, bfA, bfB, 1, 1, "vmcnt(8)", 1);
  TILE(13, bfB, bfA, 1, 0, "vmcnt(6)", 1);   // last A (A15) issued at t=12
  TILE(14, bfA, bfB, 1, 0, "vmcnt(4)", 1);   // forces A15 landed (FIFO)
  TILE(15, bfB, bfA, 0, 0, "", 0);

#undef TILE
#undef MFMA16U
#undef RD_A
#undef ISSUEA
#undef LOADB

  // ---- epilogue: LDS-staged coalesced C writes (exact-ideal granules) ----
  // Cst = float[64][128] (32KB). 4 quarters of 64 rows; quarter q written by
  // wave-row wr==q (2 waves), then all 8 waves stream it out 512B/row.
  float* Cst = (float*)smem;
  const int rr = (lane >> 4) * 4;
  const int cc = lane & 15;
#pragma unroll
  for (int q = 0; q < 4; ++q) {
    if (wr == q) {
#pragma unroll
      for (int j = 0; j < 4; j++) {
        const int colL = wc * 64 + j * 16 + cc;     // 0..127
        const float bs = bscale[n0 + colL];
        const float bi = bint[n0 + colL];
#pragma unroll
        for (int i = 0; i < 4; i++)
#pragma unroll
          for (int r = 0; r < 4; r++)
            Cst[(i * 16 + rr + r) * 128 + colL] = ((float)acc[i][j][r] + bi) * bs;
      }
    }
    WAIT_LGKM0;
    BAR;
    const size_t rowbase = (size_t)(m0 + q * 64) * N + n0;
#pragma unroll
    for (int it = 0; it < 4; ++it) {
      const int r_ = it * 16 + wid * 2 + (lane >> 5);   // 0..63
      const int c_ = (lane & 31) * 4;                    // 0..124
      float4 v = *(const float4*)&Cst[r_ * 128 + c_];
      *(float4*)&out[rowbase + (size_t)r_ * N + c_] = v;
    }
    WAIT_LGKM0;
    BAR;
  }
}

// ---------------- launch ----------------
extern "C" void kernel_launch(void* const* d_in, const int* in_sizes, int n_in,
                              void* d_out, int out_size, void* d_ws, size_t ws_size,
                              hipStream_t stream) {
  const float* hs = (const float*)d_in[0];
  const float* w = (const float*)d_in[1];
  const float* bias = (const float*)d_in[2];
  float* out = (float*)d_out;

  const long long n = (long long)in_sizes[0];     // 50331648
  const int K = K_DIM;                            // 1024
  const int O = in_sizes[2];                      // 1024
  const int M = (int)(n / K);                     // 49152

  // workspace layout
  char* ws = (char*)d_ws;
  unsigned int* amax_u = (unsigned int*)ws;                        // 4 B
  float* parts = (float*)(ws + 1024);                              // 8 KB
  float* bscale = (float*)(ws + 16384);                            // 4 KB
  float* bint = (float*)(ws + 20480);                              // 4 KB
  signed char* wq = (signed char*)(ws + 65536);                    // 1 MB (frag-ordered)
  signed char* xq = (signed char*)(ws + 65536 + 1048576);          // 48 MB (frag-ordered)

  hipFuncSetAttribute((const void*)gemm_kernel,
                      hipFuncAttributeMaxDynamicSharedMemorySize, 65536);

  const long long n4 = n / 4;
  absmax_part<<<2048, 256, 0, stream>>>(hs, parts, n4);
  absmax_fin<<<1, 256, 0, stream>>>(parts, amax_u, 2048);
  wquant_kernel<<<O, 256, 0, stream>>>(w, bias, amax_u, wq, bscale, bint);
  const int nchunk = (int)(n / 16);
  aquant_kernel<<<2048, 256, 0, stream>>>(hs, amax_u, (uint4*)xq, nchunk);

  const int nblocks = (M / BM) * (O / BN);        // 192 * 8 = 1536
  gemm_kernel<<<nblocks, 512, 65536, stream>>>(xq, wq, bscale, bint, out, M, O, K);
}

// Round 16
// 179.457 us; speedup vs baseline: 1.1974x; 1.1974x over previous
//
#include <hip/hip_runtime.h>
#include <stdint.h>

typedef int i32x4 __attribute__((ext_vector_type(4)));

#define K_DIM 1024
#define BM 256
#define BN 256
#define NKT 16   // K-tiles of 64

// Fragment-ordered int8 operand layout (producers aquant/wquant <-> consumer GEMM):
// fragment (F = row/16, T = k/64) is 1KB at offset ((F*16)+T)*1024; byte b
// (l=b>>4, j=b&15) holds value[row=F*16+(l&15)][k=T*64+(l>>4)*16+j].
// -> A gld_lds reads are 1KB contiguous; B fragments load straight to registers.

// ---------------- helpers ----------------
__device__ __forceinline__ int quant1(float v, float inv) {
  float t = rintf(v * inv);                 // round half-to-even, matches jnp.round
  t = fminf(fmaxf(t, -128.0f), 127.0f);     // clip(-n-1, n)
  return (int)t;
}

__device__ __forceinline__ void gld_lds16(const signed char* g, signed char* l) {
  typedef const __attribute__((address_space(1))) unsigned int* gp_t;
  typedef __attribute__((address_space(3))) unsigned int* lp_t;
  __builtin_amdgcn_global_load_lds((gp_t)(const void*)g, (lp_t)(void*)l, 16, 0, 0);
}

#define SB __builtin_amdgcn_sched_barrier(0)
#define BAR __builtin_amdgcn_s_barrier()
#define WAIT_LGKM0 asm volatile("s_waitcnt lgkmcnt(0)" ::: "memory")

// ---------------- 1a) absmax partials ----------------
__global__ void absmax_part(const float* __restrict__ x, float* __restrict__ parts,
                            long long n4) {
  long long i = (long long)blockIdx.x * blockDim.x + threadIdx.x;
  const long long stride = (long long)gridDim.x * blockDim.x;
  const float4* x4 = (const float4*)x;
  float m = 0.0f;
  for (; i < n4; i += stride) {
    float4 v = x4[i];
    m = fmaxf(m, fmaxf(fmaxf(fabsf(v.x), fabsf(v.y)), fmaxf(fabsf(v.z), fabsf(v.w))));
  }
#pragma unroll
  for (int off = 32; off > 0; off >>= 1) m = fmaxf(m, __shfl_down(m, off, 64));
  __shared__ float sm[4];
  const int lane = threadIdx.x & 63, wid = threadIdx.x >> 6;
  if (lane == 0) sm[wid] = m;
  __syncthreads();
  if (threadIdx.x == 0)
    parts[blockIdx.x] = fmaxf(fmaxf(sm[0], sm[1]), fmaxf(sm[2], sm[3]));
}

// ---------------- 1b) absmax final reduce ----------------
__global__ void absmax_fin(const float* __restrict__ parts, unsigned int* __restrict__ amax_u,
                           int nparts) {
  const int t = threadIdx.x;
  float m = 0.0f;
  for (int i = t; i < nparts; i += 256) m = fmaxf(m, parts[i]);
#pragma unroll
  for (int off = 32; off > 0; off >>= 1) m = fmaxf(m, __shfl_down(m, off, 64));
  __shared__ float sm[4];
  const int lane = t & 63, wid = t >> 6;
  if (lane == 0) sm[wid] = m;
  __syncthreads();
  if (t == 0)
    amax_u[0] = __float_as_uint(fmaxf(fmaxf(sm[0], sm[1]), fmaxf(sm[2], sm[3])));
}

// ---------------- 2) per-channel weight quant + bias (frag-ordered wq) ----------------
__global__ void wquant_kernel(const float* __restrict__ w, const float* __restrict__ bias,
                              const unsigned int* __restrict__ amax_u,
                              signed char* __restrict__ wq,
                              float* __restrict__ bscale, float* __restrict__ bint) {
  const int o = blockIdx.x;
  const int t = threadIdx.x;          // handles k = 4t .. 4t+3
  float4 v = ((const float4*)(w + (size_t)o * K_DIM))[t];
  float m = fmaxf(fmaxf(fabsf(v.x), fabsf(v.y)), fmaxf(fabsf(v.z), fabsf(v.w)));
#pragma unroll
  for (int off = 32; off > 0; off >>= 1) m = fmaxf(m, __shfl_down(m, off, 64));
  __shared__ float sm[4];
  __shared__ float s_scale;
  const int lane = t & 63, wid = t >> 6;
  if (lane == 0) sm[wid] = m;
  __syncthreads();
  if (t == 0) {
    float wm = fmaxf(fmaxf(sm[0], sm[1]), fmaxf(sm[2], sm[3]));
    float wsc = fmaxf(wm, 1e-8f) / 127.0f;
    float asc = fmaxf(__uint_as_float(*amax_u), 1e-8f) / 127.0f;
    float bsc = wsc * asc;
    bscale[o] = bsc;
    bint[o] = rintf(bias[o] / bsc);
    s_scale = wsc;
  }
  __syncthreads();
  const float inv = 1.0f / s_scale;
  int q0 = quant1(v.x, inv), q1 = quant1(v.y, inv), q2 = quant1(v.z, inv), q3 = quant1(v.w, inv);
  unsigned int p = (unsigned)(q0 & 255) | ((unsigned)(q1 & 255) << 8) |
                   ((unsigned)(q2 & 255) << 16) | ((unsigned)(q3 & 255) << 24);
  const int F = o >> 4, T = t >> 4;
  const int l = (((t >> 2) & 3) << 4) | (o & 15);
  const int j = (t << 2) & 15;
  *(unsigned int*)(wq + (((size_t)F << 14) + (T << 10) + (l << 4) + j)) = p;
}

// ---------------- 3) activation quant (frag-ordered xq; 256B-granule reads) ----------------
__global__ void aquant_kernel(const float* __restrict__ x, const unsigned int* __restrict__ amax_u,
                              uint4* __restrict__ q16, int nchunk) {
  const float asc = fmaxf(__uint_as_float(*amax_u), 1e-8f) / 127.0f;
  const float inv = 1.0f / asc;
  int c = blockIdx.x * blockDim.x + threadIdx.x;
  const int stride = gridDim.x * blockDim.x;
  for (; c < nchunk; c += stride) {
    const int l = c & 63, T = (c >> 6) & 15, F = c >> 10;
    const size_t src = (((size_t)(F << 4) + (l & 15)) << 10) + (T << 6) + ((l >> 4) << 4);
    const float4* s4 = (const float4*)(x + src);
    unsigned int r[4];
#pragma unroll
    for (int q = 0; q < 4; q++) {
      float4 v = s4[q];
      int q0 = quant1(v.x, inv), q1 = quant1(v.y, inv), q2 = quant1(v.z, inv), q3 = quant1(v.w, inv);
      r[q] = (unsigned)(q0 & 255) | ((unsigned)(q1 & 255) << 8) |
             ((unsigned)(q2 & 255) << 16) | ((unsigned)(q3 & 255) << 24);
    }
    q16[c] = make_uint4(r[0], r[1], r[2], r[3]);
  }
}

// ---------------- 4) int8 GEMM: R9 + register-prefetched LDS reads ----------------
// 256x256, 8 waves (2x4), wave tile 128x64, acc[8][4].
// Body t: {vmcnt; BAR; RD_A(t+1)->alt regs; ISSUEA(t+3); LOADB(t+1); MFMA(t)}.
// LDS read latency+issue hides under the 32-MFMA cluster (consumed next tile).
// Hazards: top barrier => all waves did MFMA(t-1) => buf (t-1)&3 free for
// ISSUEA(t+3); each wave's compiler B(t-1)-wait lands its A(t+1) gld_lds
// before the barrier => cross-wave visibility. vmcnt never drains mid-loop.
__global__ __launch_bounds__(512, 2) void gemm_kernel(
    const signed char* __restrict__ A, const signed char* __restrict__ W,
    const float* __restrict__ bscale, const float* __restrict__ bint,
    float* __restrict__ out, int M, int N, int K) {
  extern __shared__ __align__(16) signed char smem[];   // 65536 B: 4 x [16][1024] A bufs
  signed char* Abase = smem;

  // bijective XCD swizzle (gridDim.x % 8 == 0)
  const int nwg = gridDim.x;
  const int orig = blockIdx.x;
  const int wgid = (orig & 7) * (nwg >> 3) + (orig >> 3);
  const int nbn = N / BN;
  const int bm = wgid / nbn;
  const int bn = wgid % nbn;
  const int m0 = bm * BM, n0 = bn * BN;

  const int tid = threadIdx.x;
  const int lane = tid & 63;
  const int wid = tid >> 6;          // 8 waves
  const int wr = wid >> 2;           // 2 wave-rows
  const int wc = wid & 3;            // 4 wave-cols

  const signed char* gaf = A + (((size_t)(m0 >> 4) + wid) << 14) + (lane << 4);
  const size_t fs8 = (size_t)8 << 14;
  const signed char* gbf = W + (((size_t)(n0 >> 4) + wc * 4) << 14) + (lane << 4);

  i32x4 acc[8][4];
#pragma unroll
  for (int i = 0; i < 8; i++)
#pragma unroll
    for (int j = 0; j < 4; j++) acc[i][j] = (i32x4){0, 0, 0, 0};

  i32x4 afA[8], afB[8];
  i32x4 bfA[4], bfB[4];

#define LOADB(L, tt)                                                           \
  do {                                                                         \
    L[0] = *(const i32x4*)(gbf + ((size_t)0 << 14) + ((tt) << 10));            \
    L[1] = *(const i32x4*)(gbf + ((size_t)1 << 14) + ((tt) << 10));            \
    L[2] = *(const i32x4*)(gbf + ((size_t)2 << 14) + ((tt) << 10));            \
    L[3] = *(const i32x4*)(gbf + ((size_t)3 << 14) + ((tt) << 10));            \
  } while (0)

#define ISSUEA(tt)                                                             \
  do {                                                                         \
    gld_lds16(gaf + ((size_t)(tt) << 10),                                      \
              Abase + ((((tt) & 3) * 16 + wid) << 10));                        \
    gld_lds16(gaf + fs8 + ((size_t)(tt) << 10),                                \
              Abase + ((((tt) & 3) * 16 + wid + 8) << 10));                    \
  } while (0)

#define RD_A8(t, AF)                                                           \
  do {                                                                         \
    _Pragma("unroll") for (int i_ = 0; i_ < 8; i_++)                           \
      AF[i_] = *(const i32x4*)(Abase + ((((t) & 3) * 16 + wr * 8 + i_) << 10)  \
                               + (lane << 4));                                 \
  } while (0)

#define MFMA32(AF, U)                                                          \
  do {                                                                         \
    __builtin_amdgcn_s_setprio(1);                                             \
    _Pragma("unroll") for (int i_ = 0; i_ < 8; i_++)                           \
      _Pragma("unroll") for (int j_ = 0; j_ < 4; j_++)                         \
        acc[i_][j_] = __builtin_amdgcn_mfma_i32_16x16x64_i8(                   \
            AF[i_], U[j_], acc[i_][j_], 0, 0, 0);                              \
    __builtin_amdgcn_s_setprio(0);                                             \
  } while (0)

// body t: CA/CB = regs for MFMA(t); NA/NB = regs to fill for tile t+1
#define BODY(t, CA, NA, CB, NB, DORD, DOA, DOB, VMW)                           \
  do {                                                                         \
    asm volatile("s_waitcnt " VMW ::: "memory");                               \
    SB; BAR; SB;                                                               \
    if (DORD) RD_A8((t) + 1, NA);                                              \
    if (DOA) ISSUEA((t) + 3);                                                  \
    if (DOB) LOADB(NB, (t) + 1);                                               \
    MFMA32(CA, CB);                                                            \
  } while (0)

  // prologue: A(0..2) staged (6 loads), B(0) (4 loads); vmcnt(8) lands A(0).
  ISSUEA(0); ISSUEA(1); ISSUEA(2);
  LOADB(bfA, 0);
  asm volatile("s_waitcnt vmcnt(8)" ::: "memory");
  SB; BAR; SB;
  RD_A8(0, afA);

  BODY(0,  afA, afB, bfA, bfB, 1, 1, 1, "vmcnt(6)");
  BODY(1,  afB, afA, bfB, bfA, 1, 1, 1, "vmcnt(6)");
  BODY(2,  afA, afB, bfA, bfB, 1, 1, 1, "vmcnt(6)");
  BODY(3,  afB, afA, bfB, bfA, 1, 1, 1, "vmcnt(6)");
  BODY(4,  afA, afB, bfA, bfB, 1, 1, 1, "vmcnt(6)");
  BODY(5,  afB, afA, bfB, bfA, 1, 1, 1, "vmcnt(6)");
  BODY(6,  afA, afB, bfA, bfB, 1, 1, 1, "vmcnt(6)");
  BODY(7,  afB, afA, bfB, bfA, 1, 1, 1, "vmcnt(6)");
  BODY(8,  afA, afB, bfA, bfB, 1, 1, 1, "vmcnt(6)");
  BODY(9,  afB, afA, bfB, bfA, 1, 1, 1, "vmcnt(6)");
  BODY(10, afA, afB, bfA, bfB, 1, 1, 1, "vmcnt(6)");
  BODY(11, afB, afA, bfB, bfA, 1, 1, 1, "vmcnt(6)");
  BODY(12, afA, afB, bfA, bfB, 1, 1, 1, "vmcnt(6)");   // last ISSUEA (A15)
  BODY(13, afB, afA, bfB, bfA, 1, 0, 1, "vmcnt(6)");
  BODY(14, afA, afB, bfA, bfB, 1, 0, 1, "vmcnt(4)");   // lands A15 for RD_A8(15)
  BODY(15, afB, afA, bfB, bfA, 0, 0, 0, "vmcnt(4)");

  // all waves' MFMA(15) done before Cst overwrites the A bufs
  SB; BAR; SB;

#undef BODY
#undef MFMA32
#undef RD_A8
#undef ISSUEA
#undef LOADB

  // ---- epilogue: LDS-staged coalesced C writes (exact-ideal 196.6MB), 4x 64-row quarters ----
  float* Cst = (float*)smem;
  const int rr = (lane >> 4) * 4;
  const int cc = lane & 15;
#pragma unroll
  for (int q = 0; q < 4; ++q) {
    if (wr == (q >> 1)) {
#pragma unroll
      for (int j = 0; j < 4; j++) {
        const int colL = wc * 64 + j * 16 + cc;
        const float bs = bscale[n0 + colL];
        const float bi = bint[n0 + colL];
#pragma unroll
        for (int i2 = 0; i2 < 4; i2++) {
          const int i = (q & 1) * 4 + i2;
#pragma unroll
          for (int r = 0; r < 4; r++)
            Cst[(i2 * 16 + rr + r) * 256 + colL] = ((float)acc[i][j][r] + bi) * bs;
        }
      }
    }
    WAIT_LGKM0;
    BAR;
    const size_t rowbase = (size_t)(m0 + q * 64) * N + n0;
#pragma unroll
    for (int it = 0; it < 8; ++it) {
      const int r_ = it * 8 + wid;                  // 0..63
      float4 v = *(const float4*)&Cst[r_ * 256 + lane * 4];
      *(float4*)&out[rowbase + (size_t)r_ * N + lane * 4] = v;
    }
    WAIT_LGKM0;
    BAR;
  }
}

// ---------------- launch ----------------
extern "C" void kernel_launch(void* const* d_in, const int* in_sizes, int n_in,
                              void* d_out, int out_size, void* d_ws, size_t ws_size,
                              hipStream_t stream) {
  const float* hs = (const float*)d_in[0];
  const float* w = (const float*)d_in[1];
  const float* bias = (const float*)d_in[2];
  float* out = (float*)d_out;

  const long long n = (long long)in_sizes[0];     // 50331648
  const int K = K_DIM;                            // 1024
  const int O = in_sizes[2];                      // 1024
  const int M = (int)(n / K);                     // 49152

  // workspace layout
  char* ws = (char*)d_ws;
  unsigned int* amax_u = (unsigned int*)ws;                        // 4 B
  float* parts = (float*)(ws + 1024);                              // 8 KB
  float* bscale = (float*)(ws + 16384);                            // 4 KB
  float* bint = (float*)(ws + 20480);                              // 4 KB
  signed char* wq = (signed char*)(ws + 65536);                    // 1 MB (frag-ordered)
  signed char* xq = (signed char*)(ws + 65536 + 1048576);          // 48 MB (frag-ordered)

  hipFuncSetAttribute((const void*)gemm_kernel,
                      hipFuncAttributeMaxDynamicSharedMemorySize, 65536);

  const long long n4 = n / 4;
  absmax_part<<<2048, 256, 0, stream>>>(hs, parts, n4);
  absmax_fin<<<1, 256, 0, stream>>>(parts, amax_u, 2048);
  wquant_kernel<<<O, 256, 0, stream>>>(w, bias, amax_u, wq, bscale, bint);
  const int nchunk = (int)(n / 16);
  aquant_kernel<<<2048, 256, 0, stream>>>(hs, amax_u, (uint4*)xq, nchunk);

  const int nblocks = (M / BM) * (O / BN);        // 192 * 4 = 768
  gemm_kernel<<<nblocks, 512, 65536, stream>>>(xq, wq, bscale, bint, out, M, O, K);
}

// Round 17
// 176.065 us; speedup vs baseline: 1.2205x; 1.0193x over previous
//
#include <hip/hip_runtime.h>
#include <stdint.h>

typedef int i32x4 __attribute__((ext_vector_type(4)));

#define K_DIM 1024
#define BM 256
#define BN 256
#define NKT 16   // K-tiles of 64

// Fragment-ordered int8 operand layout (producers aquant/wquant <-> consumer GEMM):
// fragment (F = row/16, T = k/64) is 1KB at offset ((F*16)+T)*1024; byte b
// (l=b>>4, j=b&15) holds value[row=F*16+(l&15)][k=T*64+(l>>4)*16+j].
// -> A gld_lds reads are 1KB contiguous; B fragments load straight to registers.

// ---------------- helpers ----------------
__device__ __forceinline__ int quant1(float v, float inv) {
  float t = rintf(v * inv);                 // round half-to-even, matches jnp.round
  t = fminf(fmaxf(t, -128.0f), 127.0f);     // clip(-n-1, n)
  return (int)t;
}

__device__ __forceinline__ void gld_lds16(const signed char* g, signed char* l) {
  typedef const __attribute__((address_space(1))) unsigned int* gp_t;
  typedef __attribute__((address_space(3))) unsigned int* lp_t;
  __builtin_amdgcn_global_load_lds((gp_t)(const void*)g, (lp_t)(void*)l, 16, 0, 0);
}

#define SB __builtin_amdgcn_sched_barrier(0)
#define BAR __builtin_amdgcn_s_barrier()
#define WAIT_LGKM0 asm volatile("s_waitcnt lgkmcnt(0)" ::: "memory")

// ---------------- 1a) absmax partials ----------------
__global__ void absmax_part(const float* __restrict__ x, float* __restrict__ parts,
                            long long n4) {
  long long i = (long long)blockIdx.x * blockDim.x + threadIdx.x;
  const long long stride = (long long)gridDim.x * blockDim.x;
  const float4* x4 = (const float4*)x;
  float m = 0.0f;
  for (; i < n4; i += stride) {
    float4 v = x4[i];
    m = fmaxf(m, fmaxf(fmaxf(fabsf(v.x), fabsf(v.y)), fmaxf(fabsf(v.z), fabsf(v.w))));
  }
#pragma unroll
  for (int off = 32; off > 0; off >>= 1) m = fmaxf(m, __shfl_down(m, off, 64));
  __shared__ float sm[4];
  const int lane = threadIdx.x & 63, wid = threadIdx.x >> 6;
  if (lane == 0) sm[wid] = m;
  __syncthreads();
  if (threadIdx.x == 0)
    parts[blockIdx.x] = fmaxf(fmaxf(sm[0], sm[1]), fmaxf(sm[2], sm[3]));
}

// ---------------- 1b) absmax final reduce ----------------
__global__ void absmax_fin(const float* __restrict__ parts, unsigned int* __restrict__ amax_u,
                           int nparts) {
  const int t = threadIdx.x;
  float m = 0.0f;
  for (int i = t; i < nparts; i += 256) m = fmaxf(m, parts[i]);
#pragma unroll
  for (int off = 32; off > 0; off >>= 1) m = fmaxf(m, __shfl_down(m, off, 64));
  __shared__ float sm[4];
  const int lane = t & 63, wid = t >> 6;
  if (lane == 0) sm[wid] = m;
  __syncthreads();
  if (t == 0)
    amax_u[0] = __float_as_uint(fmaxf(fmaxf(sm[0], sm[1]), fmaxf(sm[2], sm[3])));
}

// ---------------- 2) per-channel weight quant + bias (frag-ordered wq) ----------------
__global__ void wquant_kernel(const float* __restrict__ w, const float* __restrict__ bias,
                              const unsigned int* __restrict__ amax_u,
                              signed char* __restrict__ wq,
                              float* __restrict__ bscale, float* __restrict__ bint) {
  const int o = blockIdx.x;
  const int t = threadIdx.x;          // handles k = 4t .. 4t+3
  float4 v = ((const float4*)(w + (size_t)o * K_DIM))[t];
  float m = fmaxf(fmaxf(fabsf(v.x), fabsf(v.y)), fmaxf(fabsf(v.z), fabsf(v.w)));
#pragma unroll
  for (int off = 32; off > 0; off >>= 1) m = fmaxf(m, __shfl_down(m, off, 64));
  __shared__ float sm[4];
  __shared__ float s_scale;
  const int lane = t & 63, wid = t >> 6;
  if (lane == 0) sm[wid] = m;
  __syncthreads();
  if (t == 0) {
    float wm = fmaxf(fmaxf(sm[0], sm[1]), fmaxf(sm[2], sm[3]));
    float wsc = fmaxf(wm, 1e-8f) / 127.0f;
    float asc = fmaxf(__uint_as_float(*amax_u), 1e-8f) / 127.0f;
    float bsc = wsc * asc;
    bscale[o] = bsc;
    bint[o] = rintf(bias[o] / bsc);
    s_scale = wsc;
  }
  __syncthreads();
  const float inv = 1.0f / s_scale;
  int q0 = quant1(v.x, inv), q1 = quant1(v.y, inv), q2 = quant1(v.z, inv), q3 = quant1(v.w, inv);
  unsigned int p = (unsigned)(q0 & 255) | ((unsigned)(q1 & 255) << 8) |
                   ((unsigned)(q2 & 255) << 16) | ((unsigned)(q3 & 255) << 24);
  const int F = o >> 4, T = t >> 4;
  const int l = (((t >> 2) & 3) << 4) | (o & 15);
  const int j = (t << 2) & 15;
  *(unsigned int*)(wq + (((size_t)F << 14) + (T << 10) + (l << 4) + j)) = p;
}

// ---------------- 3) activation quant (frag-ordered xq; 256B-granule reads) ----------------
__global__ void aquant_kernel(const float* __restrict__ x, const unsigned int* __restrict__ amax_u,
                              uint4* __restrict__ q16, int nchunk) {
  const float asc = fmaxf(__uint_as_float(*amax_u), 1e-8f) / 127.0f;
  const float inv = 1.0f / asc;
  int c = blockIdx.x * blockDim.x + threadIdx.x;
  const int stride = gridDim.x * blockDim.x;
  for (; c < nchunk; c += stride) {
    const int l = c & 63, T = (c >> 6) & 15, F = c >> 10;
    const size_t src = (((size_t)(F << 4) + (l & 15)) << 10) + (T << 6) + ((l >> 4) << 4);
    const float4* s4 = (const float4*)(x + src);
    unsigned int r[4];
#pragma unroll
    for (int q = 0; q < 4; q++) {
      float4 v = s4[q];
      int q0 = quant1(v.x, inv), q1 = quant1(v.y, inv), q2 = quant1(v.z, inv), q3 = quant1(v.w, inv);
      r[q] = (unsigned)(q0 & 255) | ((unsigned)(q1 & 255) << 8) |
             ((unsigned)(q2 & 255) << 16) | ((unsigned)(q3 & 255) << 24);
    }
    q16[c] = make_uint4(r[0], r[1], r[2], r[3]);
  }
}

// ---------------- 4) int8 GEMM: R9 pipeline, ring-6 LDS, ONE barrier per 2 tiles ----------------
// 256x256, 8 waves (2x4), wave tile 128x64, acc[8][4].
// Ring-6 A buffers (96KB) + ISSUEA(t+4): in each 2-tile window {t,t+1}, writes
// touch bufs (t+4)%6,(t+5)%6 and reads bufs t%6,(t+1)%6 -> disjoint, so one
// barrier per window suffices (WAR safe). Publication: each wave's vmcnt(8) at
// MFMA(t-1) forces A(t),A(t+1) landed before the window-top barrier.
// Barriers per K-sweep: 16 -> 8.
__global__ __launch_bounds__(512, 2) void gemm_kernel(
    const signed char* __restrict__ A, const signed char* __restrict__ W,
    const float* __restrict__ bscale, const float* __restrict__ bint,
    float* __restrict__ out, int M, int N, int K) {
  extern __shared__ __align__(16) signed char smem[];   // 98304 B: 6 x [16][1024] A bufs
  signed char* Abase = smem;

  // bijective XCD swizzle (gridDim.x % 8 == 0)
  const int nwg = gridDim.x;
  const int orig = blockIdx.x;
  const int wgid = (orig & 7) * (nwg >> 3) + (orig >> 3);
  const int nbn = N / BN;
  const int bm = wgid / nbn;
  const int bn = wgid % nbn;
  const int m0 = bm * BM, n0 = bn * BN;

  const int tid = threadIdx.x;
  const int lane = tid & 63;
  const int wid = tid >> 6;          // 8 waves
  const int wr = wid >> 2;           // 2 wave-rows
  const int wc = wid & 3;            // 4 wave-cols

  const signed char* gaf = A + (((size_t)(m0 >> 4) + wid) << 14) + (lane << 4);
  const size_t fs8 = (size_t)8 << 14;
  const signed char* gbf = W + (((size_t)(n0 >> 4) + wc * 4) << 14) + (lane << 4);

  i32x4 acc[8][4];
#pragma unroll
  for (int i = 0; i < 8; i++)
#pragma unroll
    for (int j = 0; j < 4; j++) acc[i][j] = (i32x4){0, 0, 0, 0};

  i32x4 af[8];
  i32x4 bfA[4], bfB[4];

#define LOADB(L, tt)                                                           \
  do {                                                                         \
    L[0] = *(const i32x4*)(gbf + ((size_t)0 << 14) + ((tt) << 10));            \
    L[1] = *(const i32x4*)(gbf + ((size_t)1 << 14) + ((tt) << 10));            \
    L[2] = *(const i32x4*)(gbf + ((size_t)2 << 14) + ((tt) << 10));            \
    L[3] = *(const i32x4*)(gbf + ((size_t)3 << 14) + ((tt) << 10));            \
  } while (0)

#define ISSUEA(tt)                                                             \
  do {                                                                         \
    gld_lds16(gaf + ((size_t)(tt) << 10),                                      \
              Abase + ((((tt) % 6) * 16 + wid) << 10));                        \
    gld_lds16(gaf + fs8 + ((size_t)(tt) << 10),                                \
              Abase + ((((tt) % 6) * 16 + wid + 8) << 10));                    \
  } while (0)

#define RD_A8(t)                                                               \
  do {                                                                         \
    _Pragma("unroll") for (int i_ = 0; i_ < 8; i_++)                           \
      af[i_] = *(const i32x4*)(Abase + ((((t) % 6) * 16 + wr * 8 + i_) << 10)  \
                               + (lane << 4));                                 \
  } while (0)

#define MFMA32(U)                                                              \
  do {                                                                         \
    __builtin_amdgcn_s_setprio(1);                                             \
    _Pragma("unroll") for (int i_ = 0; i_ < 8; i_++)                           \
      _Pragma("unroll") for (int j_ = 0; j_ < 4; j_++)                         \
        acc[i_][j_] = __builtin_amdgcn_mfma_i32_16x16x64_i8(                   \
            af[i_], U[j_], acc[i_][j_], 0, 0, 0);                              \
    __builtin_amdgcn_s_setprio(0);                                             \
  } while (0)

// body t: U = B regs for MFMA(t); L = B regs to fill with B(t+1)
#define BODY(t, U, L, DOB, DOA, VMW, DOVM)                                     \
  do {                                                                         \
    if (DOB) LOADB(L, (t) + 1);                                                \
    if (DOA) ISSUEA((t) + 4);                                                  \
    SB;                                                                        \
    RD_A8(t);                                                                  \
    MFMA32(U);                                                                 \
    if (DOVM) { asm volatile("s_waitcnt " VMW ::: "memory"); }                 \
  } while (0)

  // prologue: B(0) first, then A(0..3) staged (ring-6); vmcnt(6) lands B(0)+A(0).
  LOADB(bfA, 0);
  ISSUEA(0); ISSUEA(1); ISSUEA(2); ISSUEA(3);
  asm volatile("s_waitcnt vmcnt(6)" ::: "memory");
  SB; BAR; SB;

  // 8 windows of 2 tiles, ONE barrier per window
  BODY(0,  bfA, bfB, 1, 1, "vmcnt(8)", 1);
  BODY(1,  bfB, bfA, 1, 1, "vmcnt(8)", 1);
  SB; BAR; SB;
  BODY(2,  bfA, bfB, 1, 1, "vmcnt(8)", 1);
  BODY(3,  bfB, bfA, 1, 1, "vmcnt(8)", 1);
  SB; BAR; SB;
  BODY(4,  bfA, bfB, 1, 1, "vmcnt(8)", 1);
  BODY(5,  bfB, bfA, 1, 1, "vmcnt(8)", 1);
  SB; BAR; SB;
  BODY(6,  bfA, bfB, 1, 1, "vmcnt(8)", 1);
  BODY(7,  bfB, bfA, 1, 1, "vmcnt(8)", 1);
  SB; BAR; SB;
  BODY(8,  bfA, bfB, 1, 1, "vmcnt(8)", 1);
  BODY(9,  bfB, bfA, 1, 1, "vmcnt(8)", 1);
  SB; BAR; SB;
  BODY(10, bfA, bfB, 1, 1, "vmcnt(8)", 1);
  BODY(11, bfB, bfA, 1, 1, "vmcnt(8)", 1);   // last ISSUEA: A(15)
  SB; BAR; SB;
  BODY(12, bfA, bfB, 1, 0, "vmcnt(6)", 1);
  BODY(13, bfB, bfA, 1, 0, "vmcnt(4)", 1);
  SB; BAR; SB;
  BODY(14, bfA, bfB, 1, 0, "vmcnt(4)", 1);
  BODY(15, bfB, bfA, 0, 0, "vmcnt(0)", 1);

  // all waves' MFMA(15) done before Cst overwrites the A bufs
  SB; BAR; SB;

#undef BODY
#undef MFMA32
#undef RD_A8
#undef ISSUEA
#undef LOADB

  // ---- epilogue: LDS-staged coalesced C writes (exact-ideal 196.6MB), 4x 64-row quarters ----
  float* Cst = (float*)smem;
  const int rr = (lane >> 4) * 4;
  const int cc = lane & 15;
#pragma unroll
  for (int q = 0; q < 4; ++q) {
    if (wr == (q >> 1)) {
#pragma unroll
      for (int j = 0; j < 4; j++) {
        const int colL = wc * 64 + j * 16 + cc;
        const float bs = bscale[n0 + colL];
        const float bi = bint[n0 + colL];
#pragma unroll
        for (int i2 = 0; i2 < 4; i2++) {
          const int i = (q & 1) * 4 + i2;
#pragma unroll
          for (int r = 0; r < 4; r++)
            Cst[(i2 * 16 + rr + r) * 256 + colL] = ((float)acc[i][j][r] + bi) * bs;
        }
      }
    }
    WAIT_LGKM0;
    BAR;
    const size_t rowbase = (size_t)(m0 + q * 64) * N + n0;
#pragma unroll
    for (int it = 0; it < 8; ++it) {
      const int r_ = it * 8 + wid;                  // 0..63
      float4 v = *(const float4*)&Cst[r_ * 256 + lane * 4];
      *(float4*)&out[rowbase + (size_t)r_ * N + lane * 4] = v;
    }
    WAIT_LGKM0;
    BAR;
  }
}

// ---------------- launch ----------------
extern "C" void kernel_launch(void* const* d_in, const int* in_sizes, int n_in,
                              void* d_out, int out_size, void* d_ws, size_t ws_size,
                              hipStream_t stream) {
  const float* hs = (const float*)d_in[0];
  const float* w = (const float*)d_in[1];
  const float* bias = (const float*)d_in[2];
  float* out = (float*)d_out;

  const long long n = (long long)in_sizes[0];     // 50331648
  const int K = K_DIM;                            // 1024
  const int O = in_sizes[2];                      // 1024
  const int M = (int)(n / K);                     // 49152

  // workspace layout
  char* ws = (char*)d_ws;
  unsigned int* amax_u = (unsigned int*)ws;                        // 4 B
  float* parts = (float*)(ws + 1024);                              // 8 KB
  float* bscale = (float*)(ws + 16384);                            // 4 KB
  float* bint = (float*)(ws + 20480);                              // 4 KB
  signed char* wq = (signed char*)(ws + 65536);                    // 1 MB (frag-ordered)
  signed char* xq = (signed char*)(ws + 65536 + 1048576);          // 48 MB (frag-ordered)

  hipFuncSetAttribute((const void*)gemm_kernel,
                      hipFuncAttributeMaxDynamicSharedMemorySize, 98304);

  const long long n4 = n / 4;
  absmax_part<<<2048, 256, 0, stream>>>(hs, parts, n4);
  absmax_fin<<<1, 256, 0, stream>>>(parts, amax_u, 2048);
  wquant_kernel<<<O, 256, 0, stream>>>(w, bias, amax_u, wq, bscale, bint);
  const int nchunk = (int)(n / 16);
  aquant_kernel<<<2048, 256, 0, stream>>>(hs, amax_u, (uint4*)xq, nchunk);

  const int nblocks = (M / BM) * (O / BN);        // 192 * 4 = 768
  gemm_kernel<<<nblocks, 512, 98304, stream>>>(xq, wq, bscale, bint, out, M, O, K);
}